// Round 7
// baseline (53.194 us; speedup 1.0000x reference)
//
#include <hip/hip_runtime.h>
#include <math.h>

#define NHEADS 4
#define HDIM   32
#define DMODEL 128
#define SLEN   8192
#define BATCH  8
#define QKVC   384   // 3 * NHEADS * HDIM

typedef __bf16 bf16x8 __attribute__((ext_vector_type(8)));
typedef float  f32x4  __attribute__((ext_vector_type(4)));

// round-to-nearest-even f32 -> bf16 bits
static __device__ __forceinline__ unsigned short f2bf(float f) {
    union { float f; unsigned int u; } v; v.f = f;
    unsigned int r = (v.u + 0x7FFFu + ((v.u >> 16) & 1u)) >> 16;
    return (unsigned short)r;
}
// hardware cvt pack (v_cvt_pk_bf16_f32)
static __device__ __forceinline__ unsigned int pk2(float a, float b) {
    unsigned short ua = __builtin_bit_cast(unsigned short, (__bf16)a);
    unsigned short ub = __builtin_bit_cast(unsigned short, (__bf16)b);
    return (unsigned int)ua | ((unsigned int)ub << 16);
}
static __device__ __forceinline__ float bf_lo(unsigned int u) {
    union { unsigned int u; float f; } v; v.u = u << 16; return v.f;
}
static __device__ __forceinline__ float bf_hi(unsigned int u) {
    union { unsigned int u; float f; } v; v.u = u & 0xffff0000u; return v.f;
}

// ---------------------------------------------------------------------------
// Kernel P: fused prep. Segments by blockIdx.x:
//   [0,64)    : W_out f32[8192][128] -> Wt bf16 [128][8192] (transpose+cvt)
//   [64,88)   : W_qkv -> MFMA fragment buffer wfb (bf16, fragment order)
//   [88,600)  : out[b,r,j] = b_out[j]  (bias init; clears poison)
// ---------------------------------------------------------------------------
__global__ __launch_bounds__(256) void k_prep(
    const float* __restrict__ Wout, unsigned short* __restrict__ Wt,
    const float* __restrict__ Wqkv, unsigned short* __restrict__ wfb,
    const float* __restrict__ bout, float* __restrict__ out)
{
    const int tid = threadIdx.x;
    const int bx  = blockIdx.x;

    if (bx < 64) {
        __shared__ unsigned short ts[128][136];
        const float* src = Wout + (long)bx * 128 * 128;
        #pragma unroll
        for (int i = 0; i < 64; ++i) {
            const int idx = tid + i * 256;
            const int kk = idx >> 7, n = idx & 127;
            ts[n][kk] = f2bf(src[idx]);
        }
        __syncthreads();
        #pragma unroll
        for (int i = 0; i < 64; ++i) {
            const int idx = tid + i * 256;
            const int n = idx >> 7, kk = idx & 127;
            Wt[(long)n * SLEN + bx * 128 + kk] = ts[n][kk];
        }
    } else if (bx < 88) {
        const int idx  = (bx - 64) * 256 + tid;   // 0..6143
        const int lane = idx & 63;
        const int ks   = (idx >> 6) & 3;
        const int rest = idx >> 8;                // 0..23
        const int j    = rest % 6;
        const int w    = rest / 6;
        const int ch   = w * 96 + j * 16 + (lane & 15);
        const int kb   = ks * 32 + (lane >> 4) * 8;
        unsigned short t[8];
        #pragma unroll
        for (int e = 0; e < 8; ++e) t[e] = f2bf(Wqkv[(kb + e) * QKVC + ch]);
        *(uint4*)(wfb + (long)idx * 8) = *(const uint4*)t;
    } else {
        const int idx = (bx - 88) * 256 + tid;    // 0..131071
        out[idx] = bout[idx & 127];
    }
}

// ---------------------------------------------------------------------------
// Kernel 1: fused QKV projection + per-position head-mixing attention.
// 2048 blocks x 256 thr; one 32-position tile per block; ONE barrier.
// x loaded straight into MFMA B-fragments from global (no staging LDS).
// MFMA: qkv^T (W = A operand, lane owns 4 consecutive channels) -> packed
// bf16 b64 writes into XOR-swizzled qsm -> barrier -> epilogue (p,qh,half)
// with shfl_xor(1) score completion -> direct coalesced global store.
// ---------------------------------------------------------------------------
__global__ __launch_bounds__(256, 4) void k_qkv_attn_mfma(
    const float* __restrict__ x,
    const unsigned short* __restrict__ wfb,
    const float* __restrict__ bqkv,
    unsigned short* __restrict__ attn_out)   // bf16 [65536][128]
{
    __shared__ unsigned short qsm[32 * 384];  // qkv bf16, chunk-swizzled rows

    const int tid  = threadIdx.x;
    const int lane = tid & 63;
    const int wave = tid >> 6;
    const int l16  = lane & 15;
    const int lhi  = lane >> 4;
    const long p0  = (long)blockIdx.x * 32;

    // ---- load x B-fragments directly: frag(nt,ks): x[p0+nt*16+l16][ks*32+lhi*8+e]
    bf16x8 xb[2][4];
    {
        const float* r0 = x + (p0 + l16) * DMODEL + lhi * 8;
        const float* r1 = r0 + 16 * DMODEL;
        #pragma unroll
        for (int ks = 0; ks < 4; ++ks) {
            float4 a = *(const float4*)(r0 + ks * 32);
            float4 b = *(const float4*)(r0 + ks * 32 + 4);
            unsigned int t[4] = { pk2(a.x, a.y), pk2(a.z, a.w), pk2(b.x, b.y), pk2(b.z, b.w) };
            xb[0][ks] = __builtin_bit_cast(bf16x8, *(const uint4*)t);
            float4 c = *(const float4*)(r1 + ks * 32);
            float4 d = *(const float4*)(r1 + ks * 32 + 4);
            unsigned int u[4] = { pk2(c.x, c.y), pk2(c.z, c.w), pk2(d.x, d.y), pk2(d.z, d.w) };
            xb[1][ks] = __builtin_bit_cast(bf16x8, *(const uint4*)u);
        }
    }

    // ---- MFMA: qkv^T (rows = channels, cols = positions) ----
    {
        f32x4 acc[6][2];
        #pragma unroll
        for (int j = 0; j < 6; ++j)
            #pragma unroll
            for (int nt = 0; nt < 2; ++nt) acc[j][nt] = (f32x4){0.f, 0.f, 0.f, 0.f};

        const unsigned short* wbase = wfb + ((long)(wave * 24) * 64 + lane) * 8;
        #pragma unroll
        for (int ks = 0; ks < 4; ++ks) {
            #pragma unroll
            for (int j = 0; j < 6; ++j) {
                const bf16x8 wj = __builtin_bit_cast(bf16x8,
                    *(const uint4*)(wbase + (j * 4 + ks) * 512));
                acc[j][0] = __builtin_amdgcn_mfma_f32_16x16x32_bf16(wj, xb[0][ks], acc[j][0], 0, 0, 0);
                acc[j][1] = __builtin_amdgcn_mfma_f32_16x16x32_bf16(wj, xb[1][ks], acc[j][1], 0, 0, 0);
            }
        }

        // acc (+bias) -> qsm: packed b64 bf16 writes, chunk XOR-swizzled
        #pragma unroll
        for (int j = 0; j < 6; ++j) {
            const float4 bb = *(const float4*)(bqkv + wave * 96 + j * 16 + lhi * 4);
            const int c     = wave * 96 + lhi * 4 + j * 16;
            const int chunk = c >> 3;
            const int sub   = c & 7;          // 0 or 4
            #pragma unroll
            for (int nt = 0; nt < 2; ++nt) {
                const int p = nt * 16 + l16;  // p & 15 == l16
                uint2 u;
                u.x = pk2(acc[j][nt][0] + bb.x, acc[j][nt][1] + bb.y);
                u.y = pk2(acc[j][nt][2] + bb.z, acc[j][nt][3] + bb.w);
                *(uint2*)(qsm + p * 384 + (((chunk ^ l16) << 3) + sub)) = u;
            }
        }
    }
    __syncthreads();

    // ---- epilogue: thread = (p = tid>>3, qh = (tid>>1)&3, h = tid&1) ----
    {
        const int p   = tid >> 3;
        const int qh  = (tid >> 1) & 3;
        const int h   = tid & 1;
        const int psw = p & 15;
        const unsigned short* row = qsm + p * 384;
        const float scale = 0.17677669529663687f;   // 32^-0.5

        // q half: 2 chunks -> 16 f32
        float qf[16];
        {
            const int qc = qh * 12 + h * 2;
            #pragma unroll
            for (int cc = 0; cc < 2; ++cc) {
                const uint4 qv = *(const uint4*)(row + (((qc + cc) ^ psw) << 3));
                const unsigned int* w = (const unsigned int*)&qv;
                #pragma unroll
                for (int k = 0; k < 4; ++k) {
                    qf[cc * 8 + 2 * k]     = bf_lo(w[k]);
                    qf[cc * 8 + 2 * k + 1] = bf_hi(w[k]);
                }
            }
        }
        // scores: 16-d partial per thread, completed via shfl_xor(1)
        float sc[NHEADS];
        #pragma unroll
        for (int kh = 0; kh < NHEADS; ++kh) {
            float s = 0.f;
            const int kc = kh * 12 + 4 + h * 2;
            #pragma unroll
            for (int cc = 0; cc < 2; ++cc) {
                const uint4 kv = *(const uint4*)(row + (((kc + cc) ^ psw) << 3));
                const unsigned int* w = (const unsigned int*)&kv;
                #pragma unroll
                for (int k = 0; k < 4; ++k) {
                    s = fmaf(bf_lo(w[k]), qf[cc * 8 + 2 * k], s);
                    s = fmaf(bf_hi(w[k]), qf[cc * 8 + 2 * k + 1], s);
                }
            }
            sc[kh] = (s + __shfl_xor(s, 1)) * scale;
        }
        const float m = fmaxf(fmaxf(sc[0], sc[1]), fmaxf(sc[2], sc[3]));
        float ew[NHEADS], sum = 0.f;
        #pragma unroll
        for (int kh = 0; kh < NHEADS; ++kh) { ew[kh] = __expf(sc[kh] - m); sum += ew[kh]; }
        const float inv = 1.f / sum;
        #pragma unroll
        for (int kh = 0; kh < NHEADS; ++kh) ew[kh] *= inv;

        // PV: 16 output channels (d = h*16 .. h*16+16)
        float o[16];
        #pragma unroll
        for (int e = 0; e < 16; ++e) o[e] = 0.f;
        #pragma unroll
        for (int kh = 0; kh < NHEADS; ++kh) {
            const float wk = ew[kh];
            const int vc = kh * 12 + 8 + h * 2;
            #pragma unroll
            for (int cc = 0; cc < 2; ++cc) {
                const uint4 vv = *(const uint4*)(row + (((vc + cc) ^ psw) << 3));
                const unsigned int* w = (const unsigned int*)&vv;
                #pragma unroll
                for (int k = 0; k < 4; ++k) {
                    o[cc * 8 + 2 * k]     = fmaf(wk, bf_lo(w[k]), o[cc * 8 + 2 * k]);
                    o[cc * 8 + 2 * k + 1] = fmaf(wk, bf_hi(w[k]), o[cc * 8 + 2 * k + 1]);
                }
            }
        }
        // pack + direct global store (32 B per thread, wave-contiguous)
        unsigned int ow[8];
        #pragma unroll
        for (int e = 0; e < 8; ++e) ow[e] = pk2(o[2 * e], o[2 * e + 1]);
        unsigned short* dst = attn_out + (p0 + p) * DMODEL + qh * 32 + h * 16;
        *(uint4*)(dst)     = ((const uint4*)ow)[0];
        *(uint4*)(dst + 8) = ((const uint4*)ow)[1];
    }
}

// ---------------------------------------------------------------------------
// Kernel 2: final GEMM via bf16 MFMA, split-K, f32 atomicAdd into out.
//   out(1024x128) += Aflat(1024x8192 bf16) @ W(8192x128); out pre-set to bias.
// Grid: 16 M-tiles x 16 K-chunks; per block 4 stages of K=128.
// ---------------------------------------------------------------------------
__global__ __launch_bounds__(256, 2) void k_fgemm_mfma(
    const unsigned short* __restrict__ attnBf,   // [1024][8192] bf16 (flat view)
    const unsigned short* __restrict__ WtBf,     // [128][8192] bf16
    float* __restrict__ out)                     // [1024][128] f32 (bias-init)
{
    __shared__ unsigned short As[64][136];
    __shared__ unsigned short Ws[128][136];

    const int tid   = threadIdx.x;
    const int mtile = blockIdx.x >> 4;
    const int kc    = blockIdx.x & 15;
    const int lane  = tid & 63;
    const int wave  = tid >> 6;
    const int l16   = lane & 15;
    const int lhi   = lane >> 4;

    f32x4 acc[4][2];
    #pragma unroll
    for (int mf = 0; mf < 4; ++mf)
        #pragma unroll
        for (int nt = 0; nt < 2; ++nt) acc[mf][nt] = (f32x4){0.f, 0.f, 0.f, 0.f};

    for (int st = 0; st < 4; ++st) {
        const int k0 = kc * 512 + st * 128;
        __syncthreads();
        #pragma unroll
        for (int i = 0; i < 4; ++i) {
            const int c = tid + i * 256;
            const int m = c >> 4, k8 = c & 15;
            const uint4 v = *(const uint4*)(attnBf + (long)(mtile * 64 + m) * SLEN + k0 + k8 * 8);
            *(uint4*)(&As[m][k8 * 8]) = v;
        }
        #pragma unroll
        for (int i = 0; i < 8; ++i) {
            const int c = tid + i * 256;
            const int n = c >> 4, k8 = c & 15;
            const uint4 v = *(const uint4*)(WtBf + (long)n * SLEN + k0 + k8 * 8);
            *(uint4*)(&Ws[n][k8 * 8]) = v;
        }
        __syncthreads();

        #pragma unroll
        for (int ks = 0; ks < 4; ++ks) {
            const int kk = ks * 32 + lhi * 8;
            bf16x8 af[4], bfr[2];
            #pragma unroll
            for (int mf = 0; mf < 4; ++mf)
                af[mf] = __builtin_bit_cast(bf16x8, *(const uint4*)(&As[mf * 16 + l16][kk]));
            #pragma unroll
            for (int nt = 0; nt < 2; ++nt)
                bfr[nt] = __builtin_bit_cast(bf16x8, *(const uint4*)(&Ws[(wave * 2 + nt) * 16 + l16][kk]));
            #pragma unroll
            for (int mf = 0; mf < 4; ++mf)
                #pragma unroll
                for (int nt = 0; nt < 2; ++nt)
                    acc[mf][nt] = __builtin_amdgcn_mfma_f32_16x16x32_bf16(af[mf], bfr[nt], acc[mf][nt], 0, 0, 0);
        }
    }

    float* Cp = out + (long)(mtile * 64) * 128;
    #pragma unroll
    for (int mf = 0; mf < 4; ++mf) {
        #pragma unroll
        for (int nt = 0; nt < 2; ++nt) {
            const int n = (wave * 2 + nt) * 16 + l16;
            #pragma unroll
            for (int r = 0; r < 4; ++r) {
                const int m = mf * 16 + lhi * 4 + r;
                atomicAdd(&Cp[m * 128 + n], acc[mf][nt][r]);
            }
        }
    }
}

// ---------------------------------------------------------------------------
extern "C" void kernel_launch(void* const* d_in, const int* in_sizes, int n_in,
                              void* d_out, int out_size, void* d_ws, size_t ws_size,
                              hipStream_t stream)
{
    const float* x    = (const float*)d_in[0];
    const float* Wqkv = (const float*)d_in[1];
    const float* bqkv = (const float*)d_in[2];
    const float* Wout = (const float*)d_in[3];
    const float* bout = (const float*)d_in[4];
    float* out = (float*)d_out;

    // ws: [0,16MB) attn bf16 | [16,18) Wt bf16 | [18MB..) wfb bf16
    unsigned short* attnBf = (unsigned short*)d_ws;
    unsigned short* WtBf   = (unsigned short*)((char*)d_ws + (16u << 20));
    unsigned short* wfb    = (unsigned short*)((char*)d_ws + (18u << 20));

    k_prep<<<600, 256, 0, stream>>>(Wout, WtBf, Wqkv, wfb, bout, out);
    k_qkv_attn_mfma<<<2048, 256, 0, stream>>>(x, wfb, bqkv, attnBf);
    k_fgemm_mfma<<<256, 256, 0, stream>>>(attnBf, WtBf, out);
}